// Round 1
// 482.311 us; speedup vs baseline: 1.0033x; 1.0033x over previous
//
#include <hip/hip_runtime.h>
#include <math.h>

// ---------------- constants ----------------
#define EMB   1024
#define NH    16
#define HD    64
#define BATCH 4
#define LSEQ  1024
#define NTOK  (BATCH*LSEQ)          // 4096
#define SCALING 0.39528470752104744f // (64*0.1)^-0.5

typedef __attribute__((ext_vector_type(8))) short short8;   // 8 bf16 = 4 VGPRs
typedef __attribute__((ext_vector_type(4))) float f32x4;

__device__ __forceinline__ float bf2f(short s) {
    union { float f; unsigned u; } x; x.u = ((unsigned)(unsigned short)s) << 16; return x.f;
}
__device__ __forceinline__ short f2bf(float f) {
    union { float f; unsigned u; } x; x.f = f;
    unsigned r = x.u + 0x7fff + ((x.u >> 16) & 1);
    return (short)(r >> 16);
}

__device__ __forceinline__ void glds16(const void* g, void* l) {
    __builtin_amdgcn_global_load_lds(
        (const __attribute__((address_space(1))) void*)g,
        (__attribute__((address_space(3))) void*)l, 16, 0, 0);
}

// ================= Kernel 0: f32 -> bf16 conversion (all 3 tensors fused) ==
// chunk = 8 elements. Segment boundaries are multiples of 256 chunks, so the
// branch is block-uniform.
#define QCHUNKS  (4096*1024/8)              // 524288
#define WCHUNKS  (3072*1024/8)              // 393216
#define WOCHUNKS (1024*1024/8)              // 131072
__global__ __launch_bounds__(256) void cvt_all(
    const float* __restrict__ q, const float* __restrict__ wqkv,
    const float* __restrict__ wo,
    short* __restrict__ xb, short* __restrict__ wb, short* __restrict__ wob)
{
    int c = blockIdx.x * 256 + threadIdx.x;
    const float* src; short* dst; int off;
    if (c < QCHUNKS)                { src = q;    dst = xb;  off = c; }
    else if (c < QCHUNKS + WCHUNKS) { src = wqkv; dst = wb;  off = c - QCHUNKS; }
    else                            { src = wo;   dst = wob; off = c - QCHUNKS - WCHUNKS; }
    int i = off * 8;
    float4 a = *(const float4*)(src + i);
    float4 b = *(const float4*)(src + i + 4);
    short8 o;
    o[0] = f2bf(a.x); o[1] = f2bf(a.y); o[2] = f2bf(a.z); o[3] = f2bf(a.w);
    o[4] = f2bf(b.x); o[5] = f2bf(b.y); o[6] = f2bf(b.z); o[7] = f2bf(b.w);
    *(short8*)(dst + i) = o;
}

// ================= Kernel 1: QKV GEMM =================
// qkv[n][f] = sum_e X[n][e]*Wqkv[f][e] + bqkv[f];  scatter to per-head Q/K/V ws.
// M=4096, N=3072, K=1024.  128x128 tile, BK=32, 4 waves each 64x64. (m97 structure)
__global__ __launch_bounds__(256) void qkv_gemm(
    const short* __restrict__ X, const short* __restrict__ W,
    const float* __restrict__ bqkv,
    short* __restrict__ qws, short* __restrict__ kws, short* __restrict__ vws)
{
    __shared__ short As[128 * 32];
    __shared__ short Bs[128 * 32];
    const int tid = threadIdx.x;
    const int wave = tid >> 6, lane = tid & 63;
    const int quad = lane >> 4, l16 = lane & 15;
    const int m0 = blockIdx.y * 128, n0 = blockIdx.x * 128;
    const int wm = (wave >> 1) * 64, wn = (wave & 1) * 64;

    f32x4 acc[4][4] = {};

    const int srow = wave * 16 + (lane >> 2);      // staging row within 64-row half
    const int scol = (lane & 3) * 16;              // bytes within the 64-byte row

    const char* gA = (const char*)X + (size_t)(m0 + srow) * 2048 + scol;
    const char* gB = (const char*)W + (size_t)(n0 + srow) * 2048 + scol;
    char* lA = (char*)As + wave * 1024 + lane * 16;
    char* lB = (char*)Bs + wave * 1024 + lane * 16;

    for (int kt = 0; kt < 1024; kt += 32) {
        __syncthreads();
        const char* ga = gA + kt * 2;
        const char* gb = gB + kt * 2;
        glds16(ga, lA);
        glds16(ga + (size_t)64 * 2048, lA + 4096);
        glds16(gb, lB);
        glds16(gb + (size_t)64 * 2048, lB + 4096);
        __syncthreads();   // drains vmcnt incl. global_load_lds

        short8 af[4], bf[4];
        #pragma unroll
        for (int i = 0; i < 4; i++)
            af[i] = *(const short8*)((const char*)As + (wm + i * 16 + l16) * 64 + quad * 16);
        #pragma unroll
        for (int j = 0; j < 4; j++)
            bf[j] = *(const short8*)((const char*)Bs + (wn + j * 16 + l16) * 64 + quad * 16);
        #pragma unroll
        for (int i = 0; i < 4; i++)
            #pragma unroll
            for (int j = 0; j < 4; j++)
                acc[i][j] = __builtin_amdgcn_mfma_f32_16x16x32_bf16(af[i], bf[j], acc[i][j], 0, 0, 0);
    }

    // epilogue: scatter to q/k/v workspace, layout [b*NH+h][l][d]
    #pragma unroll
    for (int i = 0; i < 4; i++) {
        #pragma unroll
        for (int j = 0; j < 4; j++) {
            #pragma unroll
            for (int r = 0; r < 4; r++) {
                int gm = m0 + wm + i * 16 + quad * 4 + r;   // token index
                int gn = n0 + wn + j * 16 + l16;            // feature in [0,3072)
                float v = acc[i][j][r] + bqkv[gn];
                int part = gn >> 10;
                int cc = gn & 1023;
                int h = cc >> 6, d = cc & 63;
                int b = gm >> 10, l = gm & 1023;
                size_t dst = (((size_t)(b * NH + h)) * LSEQ + l) * HD + d;
                if (part == 0)      qws[dst] = f2bf(v * SCALING);
                else if (part == 1) kws[dst] = f2bf(v);
                else                vws[dst] = f2bf(v);
            }
        }
    }
}

// ================= Kernel 2: flash attention =================
// One block = one (b,h) and a 64-row Q tile. K/V tiles of 128 keys.
// Each wave owns 16 Q rows (Q frags held in registers). Online softmax.
// LDS 51 KB -> 3 blocks/CU. K staged via global_load_lds with XOR-swizzled
// source (T2-style, unit = 16 B, xor by row&7). V transposed into Vt with the
// key-unit XOR-swizzled by (d>>3)&7 to kill the 8-way write conflict.
__global__ __launch_bounds__(256, 3) void attn_kernel(
    const short* __restrict__ qws, const short* __restrict__ kws,
    const short* __restrict__ vws, const float* __restrict__ bias,
    const unsigned char* __restrict__ mask, short* __restrict__ att)
{
    __shared__ short Ks[128 * 64];     // linear [row][128B], 16B units swizzled
    __shared__ short Vt[64 * 136];     // V^T [d][key], stride 136, key-units swizzled
    __shared__ short Ps[4 * 16 * 136]; // per-wave P in A-layout, stride 136

    const int qt = blockIdx.x;        // 16 q-tiles
    const int bh = blockIdx.y;        // 64 (b,h)
    const int b = bh >> 4;
    const int tid = threadIdx.x, wave = tid >> 6, lane = tid & 63;
    const int quad = lane >> 4, l16 = lane & 15;

    const short* Qg = qws + (size_t)bh * LSEQ * HD + (size_t)qt * 64 * HD;
    const short* Kg = kws + (size_t)bh * LSEQ * HD;
    const short* Vg = vws + (size_t)bh * LSEQ * HD;
    const float* Bg = bias + (size_t)bh * LSEQ * LSEQ;

    // Q fragments straight from global into registers (one-time).
    // A-frag: row = wave*16 + l16, k = ks*32 + quad*8 + j
    short8 qf[2];
    #pragma unroll
    for (int ks = 0; ks < 2; ks++)
        qf[ks] = *(const short8*)(Qg + (wave * 16 + l16) * HD + ks * 32 + quad * 8);

    float m_r[4], l_r[4];
    f32x4 o[4] = {};
    #pragma unroll
    for (int r = 0; r < 4; r++) { m_r[r] = -INFINITY; l_r[r] = 0.0f; }

    const int qrow_g = qt * 64 + wave * 16 + quad * 4;   // + r
    const float* Bp = Bg + (size_t)qrow_g * LSEQ + l16;
    const unsigned char* Mp = mask + (size_t)b * LSEQ + l16;

    for (int kt0 = 0; kt0 < LSEQ; kt0 += 128) {
        // ---- issue all independent global loads first (overlap staging+barriers)
        float bv[8][4];
        #pragma unroll
        for (int ni = 0; ni < 8; ni++)
            #pragma unroll
            for (int r = 0; r < 4; r++)
                bv[ni][r] = Bp[(size_t)r * LSEQ + kt0 + ni * 16];
        unsigned char mk[8];
        #pragma unroll
        for (int ni = 0; ni < 8; ni++) mk[ni] = Mp[kt0 + ni * 16];
        short8 vst[4];
        #pragma unroll
        for (int i = 0; i < 4; i++) {
            int c = i * 256 + tid;
            int row = c >> 3, c8 = c & 7;
            vst[i] = *(const short8*)(Vg + (size_t)(kt0 + row) * HD + c8 * 8);
        }

        __syncthreads();   // previous tile's consumers done with Ks/Vt

        // ---- K tile via global_load_lds, source-swizzled (LDS linear)
        // LDS byte c*16 holds global unit u = (c&7) ^ (row&7) of row c>>3.
        #pragma unroll
        for (int i = 0; i < 4; i++) {
            int c = i * 256 + tid;
            int row = c >> 3;
            int u = (c & 7) ^ (row & 7);
            glds16((const char*)Kg + (size_t)(kt0 + row) * 128 + u * 16,
                   (char*)Ks + c * 16);
        }
        // ---- V transpose scatter, swizzled: elem V[key][d] at
        // Vt[d*136 + (((key>>3) ^ ((d>>3)&7)))*8 + (key&7)]
        #pragma unroll
        for (int i = 0; i < 4; i++) {
            int c = i * 256 + tid;
            int row = c >> 3, c8 = c & 7;
            int rl = row & 7, ru = row >> 3;
            #pragma unroll
            for (int j = 0; j < 8; j++) {
                int d = c8 * 8 + j;               // d>>3 == c8
                Vt[d * 136 + ((ru ^ c8) & 15) * 8 + rl] = vst[i][j];
            }
        }
        __syncthreads();

        // ---- S = Q K^T : 16 rows x 128 cols per wave
        f32x4 s[8] = {};
        #pragma unroll
        for (int ni = 0; ni < 8; ni++) {
            int krow = ni * 16 + l16;
            #pragma unroll
            for (int ks = 0; ks < 2; ks++) {
                int u = (ks * 4 + quad) ^ (krow & 7);
                short8 kf = *(const short8*)((const char*)Ks + krow * 128 + u * 16);
                s[ni] = __builtin_amdgcn_mfma_f32_16x16x32_bf16(qf[ks], kf, s[ni], 0, 0, 0);
            }
        }

        // ---- bias + mask (bias already in registers)
        #pragma unroll
        for (int ni = 0; ni < 8; ni++) {
            #pragma unroll
            for (int r = 0; r < 4; r++) {
                float val = s[ni][r] + bv[ni][r];
                s[ni][r] = mk[ni] ? -INFINITY : val;
            }
        }

        // ---- online softmax per row (a row's 16 column-lanes live in one quad)
        #pragma unroll
        for (int r = 0; r < 4; r++) {
            float mx = s[0][r];
            #pragma unroll
            for (int ni = 1; ni < 8; ni++) mx = fmaxf(mx, s[ni][r]);
            #pragma unroll
            for (int off = 1; off < 16; off <<= 1)
                mx = fmaxf(mx, __shfl_xor(mx, off, 64));
            float mnew = fmaxf(m_r[r], mx);
            float alpha = (m_r[r] == -INFINITY) ? 0.0f : __expf(m_r[r] - mnew);
            m_r[r] = mnew;
            float sum = 0.0f;
            #pragma unroll
            for (int ni = 0; ni < 8; ni++) {
                float p = __expf(s[ni][r] - mnew);
                s[ni][r] = p;
                sum += p;
            }
            #pragma unroll
            for (int off = 1; off < 16; off <<= 1)
                sum += __shfl_xor(sum, off, 64);
            l_r[r] = l_r[r] * alpha + sum;
            #pragma unroll
            for (int ni2 = 0; ni2 < 4; ni2++) o[ni2][r] *= alpha;
            // write P row to wave-private LDS (A-layout source)
            #pragma unroll
            for (int ni = 0; ni < 8; ni++)
                Ps[wave * 2176 + (quad * 4 + r) * 136 + ni * 16 + l16] = f2bf(s[ni][r]);
        }

        // ---- O += P V  (A-frag from Ps, B-frag from swizzled Vt)
        #pragma unroll
        for (int ks = 0; ks < 4; ks++) {
            short8 pf = *(const short8*)((const char*)Ps + wave * 4352 + l16 * 272 + ks * 64 + quad * 16);
            #pragma unroll
            for (int ni2 = 0; ni2 < 4; ni2++) {
                int d = ni2 * 16 + l16;
                int u = (ks * 4 + quad) ^ ((d >> 3) & 7);
                short8 vf = *(const short8*)((const char*)Vt + d * 272 + u * 16);
                o[ni2] = __builtin_amdgcn_mfma_f32_16x16x32_bf16(pf, vf, o[ni2], 0, 0, 0);
            }
        }
    }

    // normalize + write att[b][l][h*64+d] (bf16 ws, feeds out_gemm)
    const int h = bh & 15;
    #pragma unroll
    for (int r = 0; r < 4; r++) {
        float inv = 1.0f / l_r[r];
        int lq = qt * 64 + wave * 16 + quad * 4 + r;
        #pragma unroll
        for (int ni2 = 0; ni2 < 4; ni2++) {
            int d = ni2 * 16 + l16;
            att[((size_t)(b * LSEQ + lq)) * EMB + h * HD + d] = f2bf(o[ni2][r] * inv);
        }
    }
}

// ================= Kernel 3: output projection =================
// out[n][f] = sum_e att[n][e]*Wo[f][e] + bo[f].  M=4096, N=1024, K=1024. f32 out.
// 128x64 tile -> 512 blocks = 2 blocks/CU (was 256 = 1/CU, barrier stalls exposed).
__global__ __launch_bounds__(256) void out_gemm(
    const short* __restrict__ Xa, const short* __restrict__ Wo,
    const float* __restrict__ bo, float* __restrict__ out)
{
    __shared__ short As[128 * 32];
    __shared__ short Bs[64 * 32];
    const int tid = threadIdx.x;
    const int wave = tid >> 6, lane = tid & 63;
    const int quad = lane >> 4, l16 = lane & 15;
    const int m0 = blockIdx.y * 128, n0 = blockIdx.x * 64;
    const int wm = (wave >> 1) * 64, wn = (wave & 1) * 32;

    f32x4 acc[4][2] = {};

    const int srow = wave * 16 + (lane >> 2);
    const int scol = (lane & 3) * 16;
    const char* gA = (const char*)Xa + (size_t)(m0 + srow) * 2048 + scol;
    const char* gB = (const char*)Wo + (size_t)(n0 + (tid >> 2)) * 2048 + (tid & 3) * 16;
    char* lA = (char*)As + wave * 1024 + lane * 16;
    char* lB = (char*)Bs + tid * 16;

    for (int kt = 0; kt < 1024; kt += 32) {
        __syncthreads();
        const char* ga = gA + kt * 2;
        glds16(ga, lA);
        glds16(ga + (size_t)64 * 2048, lA + 4096);
        glds16(gB + kt * 2, lB);
        __syncthreads();

        short8 af[4], bf[2];
        #pragma unroll
        for (int i = 0; i < 4; i++)
            af[i] = *(const short8*)((const char*)As + (wm + i * 16 + l16) * 64 + quad * 16);
        #pragma unroll
        for (int j = 0; j < 2; j++)
            bf[j] = *(const short8*)((const char*)Bs + (wn + j * 16 + l16) * 64 + quad * 16);
        #pragma unroll
        for (int i = 0; i < 4; i++)
            #pragma unroll
            for (int j = 0; j < 2; j++)
                acc[i][j] = __builtin_amdgcn_mfma_f32_16x16x32_bf16(af[i], bf[j], acc[i][j], 0, 0, 0);
    }

    #pragma unroll
    for (int i = 0; i < 4; i++) {
        #pragma unroll
        for (int j = 0; j < 2; j++) {
            #pragma unroll
            for (int r = 0; r < 4; r++) {
                int gm = m0 + wm + i * 16 + quad * 4 + r;
                int gn = n0 + wn + j * 16 + l16;
                out[(size_t)gm * EMB + gn] = acc[i][j][r] + bo[gn];
            }
        }
    }
}

// ================= launch =================
extern "C" void kernel_launch(void* const* d_in, const int* in_sizes, int n_in,
                              void* d_out, int out_size, void* d_ws, size_t ws_size,
                              hipStream_t stream) {
    const float* query = (const float*)d_in[0];          // (4,1024,1024) f32
    const unsigned char* mask = (const unsigned char*)d_in[1]; // (4,1024) bool
    const float* bias = (const float*)d_in[2];           // (64,1024,1024) f32
    const float* Wqkv = (const float*)d_in[3];           // (3072,1024) f32
    const float* bqkv = (const float*)d_in[4];           // (3072,) f32
    const float* Wo   = (const float*)d_in[5];           // (1024,1024) f32
    const float* bo   = (const float*)d_in[6];           // (1024,) f32
    float* out = (float*)d_out;                          // (4,1024,1024) f32

    // workspace layout (bf16 shorts)
    short* Xb  = (short*)d_ws;                       // 4096*1024
    short* Wb  = Xb  + (size_t)4096 * 1024;          // 3072*1024
    short* Wob = Wb  + (size_t)3072 * 1024;          // 1024*1024
    short* qws = Wob + (size_t)1024 * 1024;          // 64*1024*64
    short* kws = qws + (size_t)64 * 1024 * 64;
    short* vws = kws + (size_t)64 * 1024 * 64;
    short* att = vws + (size_t)64 * 1024 * 64;       // 4096*1024

    cvt_all<<<dim3((QCHUNKS + WCHUNKS + WOCHUNKS) / 256), 256, 0, stream>>>(
        query, Wqkv, Wo, Xb, Wb, Wob);

    qkv_gemm<<<dim3(24, 32), 256, 0, stream>>>(Xb, Wb, bqkv, qws, kws, vws);
    attn_kernel<<<dim3(16, 64), 256, 0, stream>>>(qws, kws, vws, bias, mask, att);
    out_gemm<<<dim3(16, 32), 256, 0, stream>>>(att, Wob, bo, out);
}